// Round 8
// baseline (373.270 us; speedup 1.0000x reference)
//
#include <hip/hip_runtime.h>
#include <hip/hip_bf16.h>
#include <cstdint>
#include <cstddef>

#define DEV __device__ __forceinline__

typedef __attribute__((ext_vector_type(8))) short short8;
typedef __attribute__((ext_vector_type(4))) float f32x4;

constexpr int Dm  = 256;
constexpr int Qn  = 128;
constexpr int Cn  = 512;
constexpr int Bn  = 4;

DEV unsigned short f2bf(float f){
  unsigned int u = __builtin_bit_cast(unsigned int, f);
  u += 0x7fffu + ((u >> 16) & 1u);
  return (unsigned short)(u >> 16);
}
DEV unsigned int pk2(float a, float b){
  return (unsigned int)f2bf(a) | ((unsigned int)f2bf(b) << 16);
}

DEV f32x4 mfma16(short8 a, short8 b, f32x4 c){
  return __builtin_amdgcn_mfma_f32_16x16x32_bf16(a, b, c, 0, 0, 0);
}

// 16x16x32 fragment load from XOR-swizzled LDS tile (rowbytes bytes/row) — for gemm_kernel
DEV short8 ldfrag(const unsigned short* buf, int rowbytes, int row0, int ks, int l){
  int r = row0 + (l & 15);
  int byte = (ks * 64 + ((l >> 4) * 16)) ^ ((r & 7) << 4);
  return *(const short8*)((const char*)buf + r * rowbytes + byte);
}

// ---------------------------------------------------------------- converts + weight packs
// pack W[f][d] into the fragment image: byte f*512 + ((d8*16) ^ ((f&15)<<4))
DEV void packw(unsigned short* dst, const float* src, int j){
  int f = j >> 8, d = j & 255;
  int d8 = d >> 3, e = d & 7;
  int byte = (d8 * 16) ^ ((f & 15) << 4);
  dst[f * 256 + (byte >> 1) + e] = f2bf(src[j]);
}

__global__ __launch_bounds__(256) void conv_all_kernel(
    const float* inw, unsigned short* inw_bf,
    const float* aow, unsigned short* aow_bf,
    const float* ow,  unsigned short* ow_bf,
    const float* f1w, unsigned short* f1w_bf,
    const float* f2w, unsigned short* f2w_bf,
    const float* m1w, unsigned short* w1pk,
    const float* m2w, unsigned short* w2pk,
    const float* vw,  unsigned short* wvpk)
{
  const int total = 196608 + 65536 + 65536 + 262144 + 262144 + 3 * 65536;
  for (int i = blockIdx.x * 256 + threadIdx.x; i < total; i += gridDim.x * 256){
    int j = i;
    if (j < 196608){ inw_bf[j] = f2bf(inw[j]); continue; } j -= 196608;
    if (j < 65536) { aow_bf[j] = f2bf(aow[j]); continue; } j -= 65536;
    if (j < 65536) { ow_bf[j]  = f2bf(ow[j]);  continue; } j -= 65536;
    if (j < 262144){ f1w_bf[j] = f2bf(f1w[j]); continue; } j -= 262144;
    if (j < 262144){ f2w_bf[j] = f2bf(f2w[j]); continue; } j -= 262144;
    if (j < 65536) { packw(w1pk, m1w, j); continue; } j -= 65536;
    if (j < 65536) { packw(w2pk, m2w, j); continue; } j -= 65536;
    packw(wvpk, vw, j);
  }
}

// ---------------------------------------------------------------- layernorm
__global__ __launch_bounds__(256) void ln_kernel(
    const float* __restrict__ in, const float* __restrict__ g, const float* __restrict__ bt,
    const float* __restrict__ addp,
    float* __restrict__ outF, unsigned short* __restrict__ outA, unsigned short* __restrict__ outB)
{
  const int r = blockIdx.x, t = threadIdx.x;
  float x = in[(size_t)r * 256 + t];
  float s = x, s2 = x * x;
  #pragma unroll
  for (int m = 1; m < 64; m <<= 1){ s += __shfl_xor(s, m, 64); s2 += __shfl_xor(s2, m, 64); }
  __shared__ float ls[8];
  int w = t >> 6, l = t & 63;
  if (l == 0){ ls[w] = s; ls[4 + w] = s2; }
  __syncthreads();
  s  = ls[0] + ls[1] + ls[2] + ls[3];
  s2 = ls[4] + ls[5] + ls[6] + ls[7];
  float mean = s * (1.f / 256.f);
  float var  = s2 * (1.f / 256.f) - mean * mean;
  float y = (x - mean) * rsqrtf(var + 1e-5f) * g[t] + bt[t];
  size_t o = (size_t)r * 256 + t;
  if (outF) outF[o] = y;
  if (outA) outA[o] = f2bf(y);
  if (outB) outB[o] = f2bf(y + addp[o]);
}

// ---------------------------------------------------------------- generic GEMM (small mats)
__global__ __launch_bounds__(256, 4) void gemm_kernel(
    const unsigned short* __restrict__ A, const unsigned short* __restrict__ W,
    const float* __restrict__ bias, const float* __restrict__ resid,
    float* __restrict__ Cf, unsigned short* __restrict__ Cb,
    int M, int N, int K, float alpha, int relu)
{
  __shared__ unsigned short As[64 * 64];
  __shared__ unsigned short Ws[64 * 64];
  const int tid = threadIdx.x;
  const int l = tid & 63;
  const int w = tid >> 6;
  const int wm = w >> 1, wn = w & 1;
  const int bm = blockIdx.x * 64, bn = blockIdx.y * 64;
  f32x4 acc[2][2] = {{{0,0,0,0},{0,0,0,0}},{{0,0,0,0},{0,0,0,0}}};

  for (int kc = 0; kc < K; kc += 64){
    __syncthreads();
    #pragma unroll
    for (int i = 0; i < 2; ++i){
      int idx = tid + i * 256;
      int r = idx >> 3, s = idx & 7;
      int byte = (s * 16) ^ ((r & 7) << 4);
      *(short8*)((char*)As + r * 128 + byte) = *(const short8*)(A + (size_t)(bm + r) * K + kc + s * 8);
      *(short8*)((char*)Ws + r * 128 + byte) = *(const short8*)(W + (size_t)(bn + r) * K + kc + s * 8);
    }
    __syncthreads();
    #pragma unroll
    for (int ks = 0; ks < 2; ++ks){
      short8 af[2], bf[2];
      af[0] = ldfrag(As, 128, wm * 32,      ks, l);
      af[1] = ldfrag(As, 128, wm * 32 + 16, ks, l);
      bf[0] = ldfrag(Ws, 128, wn * 32,      ks, l);
      bf[1] = ldfrag(Ws, 128, wn * 32 + 16, ks, l);
      #pragma unroll
      for (int i = 0; i < 2; ++i)
        #pragma unroll
        for (int j = 0; j < 2; ++j)
          acc[i][j] = mfma16(af[i], bf[j], acc[i][j]);
    }
  }
  #pragma unroll
  for (int i = 0; i < 2; ++i)
  #pragma unroll
  for (int j = 0; j < 2; ++j){
    int col = bn + wn * 32 + j * 16 + (l & 15);
    float bv = bias ? bias[col] : 0.f;
    #pragma unroll
    for (int u = 0; u < 4; ++u){
      int row = bm + wm * 32 + i * 16 + ((l >> 4) << 2) + u;
      float v = alpha * acc[i][j][u] + bv;
      if (relu) v = fmaxf(v, 0.f);
      if (resid) v += resid[(size_t)row * N + col];
      if (Cf) Cf[(size_t)row * N + col] = v;
      if (Cb) Cb[(size_t)row * N + col] = f2bf(v);
    }
  }
}

// ---------------------------------------------------------------- self-attention
__global__ __launch_bounds__(256) void attn_kernel(
    const float* __restrict__ qkp, const float* __restrict__ vp,
    unsigned short* __restrict__ attn_o)
{
  __shared__ float ks[128][33];
  __shared__ float vs[128][33];
  __shared__ float sc[128][129];
  const int bh = blockIdx.x;
  const int b = bh >> 3, h = bh & 7;
  const int tid = threadIdx.x;
  const int lrow = tid >> 1;
  const int half = tid & 1;
  {
    int s = tid >> 1;
    int d0 = half * 16;
    const float* kp = qkp + ((size_t)s * Bn + b) * 512 + 256 + h * 32 + d0;
    const float* vv = vp  + ((size_t)s * Bn + b) * 256 +       h * 32 + d0;
    #pragma unroll
    for (int d = 0; d < 16; d += 4){
      *(float4*)&ks[s][d0 + d] = *(const float4*)(kp + d);
      *(float4*)&vs[s][d0 + d] = *(const float4*)(vv + d);
    }
  }
  __syncthreads();
  float qv[32];
  const float* qp = qkp + ((size_t)lrow * Bn + b) * 512 + h * 32;
  #pragma unroll
  for (int d = 0; d < 32; ++d) qv[d] = qp[d];
  const float scale = 0.17677669529663687f;
  float mloc = -1e30f;
  for (int s2 = 0; s2 < 64; ++s2){
    int s = half * 64 + s2;
    float dot = 0.f;
    #pragma unroll
    for (int d = 0; d < 32; ++d) dot += qv[d] * ks[s][d];
    dot *= scale;
    sc[lrow][s] = dot;
    mloc = fmaxf(mloc, dot);
  }
  float m = fmaxf(mloc, __shfl_xor(mloc, 1, 64));
  float sum = 0.f;
  for (int s2 = 0; s2 < 64; ++s2){
    int s = half * 64 + s2;
    float e = __expf(sc[lrow][s] - m);
    sum += e;
    sc[lrow][s] = e;
  }
  sum += __shfl_xor(sum, 1, 64);
  float inv = 1.f / sum;
  float o[32];
  #pragma unroll
  for (int d = 0; d < 32; ++d) o[d] = 0.f;
  for (int s2 = 0; s2 < 64; ++s2){
    int s = half * 64 + s2;
    float e = sc[lrow][s];
    #pragma unroll
    for (int d = 0; d < 32; ++d) o[d] += e * vs[s][d];
  }
  #pragma unroll
  for (int d = 0; d < 32; ++d){
    o[d] += __shfl_xor(o[d], 1, 64);
    o[d] *= inv;
  }
  unsigned short* op = attn_o + ((size_t)lrow * Bn + b) * 256 + h * 32 + half * 16;
  #pragma unroll
  for (int d = 0; d < 16; ++d) op[d] = f2bf(o[half * 16 + d]);
}

// ---------------------------------------------------------------- fused relation branch
// One block per qb, 512 threads = 8 waves; wave w owns f in [w*32, w*32+32).
// ALL three weight f-slices in registers (192/thread). LDS: double-buffered
// x/y/h 16-c tiles (48 KB) + t2/b1 rows. Software pipeline:
//   barrier A -> phase1(t): h=relu(x@W1+b1) -> pack(t+1) -> phase2(t-1):
//   e=exp((h@W2)/16), acc += e*(y@Wv) -> barrier B -> stage x/y(t+1), load(t+2).
// b2 cancels in ta/la ratio; vb added in epilogue. Global traffic = rel read only.
__global__ __launch_bounds__(512, 2) void relfused_kernel(
    const float* __restrict__ rel, const float* __restrict__ memp,
    const float* __restrict__ t22f,
    const unsigned short* __restrict__ W1g,
    const unsigned short* __restrict__ W2g,
    const unsigned short* __restrict__ Wvg,
    const float* __restrict__ b1,
    const float* __restrict__ vbp,
    unsigned short* __restrict__ trel)
{
  __shared__ unsigned short xb[2][4096];   // 16 KB
  __shared__ unsigned short yb[2][4096];   // 16 KB
  __shared__ unsigned short hb[2][4096];   // 16 KB
  __shared__ float t2s[256];
  __shared__ float b1s[256];

  const int qb = blockIdx.x;
  const int q = qb >> 2, b = qb & 3;
  const int tid = threadIdx.x;
  const int w = tid >> 6, l = tid & 63;
  const int l15 = l & 15, lg = l >> 4;

  if (tid < 256){ t2s[tid] = t22f[(size_t)qb * 256 + tid]; b1s[tid] = b1[tid]; }

  // ---- all weight A-fragments -> registers (192 regs; long-lived, AGPR-friendly)
  short8 w1r[2][8], w2r[2][8], wvr[2][8];
  #pragma unroll
  for (int j = 0; j < 2; ++j){
    int f = w * 32 + j * 16 + l15;
    #pragma unroll
    for (int kc = 0; kc < 8; ++kc){
      int byte = f * 512 + ((kc * 64 + lg * 16) ^ ((f & 15) << 4));
      w1r[j][kc] = *(const short8*)((const char*)W1g + byte);
      w2r[j][kc] = *(const short8*)((const char*)W2g + byte);
      wvr[j][kc] = *(const short8*)((const char*)Wvg + byte);
    }
  }

  const int srow = tid >> 5, d8 = tid & 31;
  const int toff = srow * 512 + ((d8 * 16) ^ ((srow & 15) << 4));
  const float* relbase = rel + (((size_t)q * 512 + srow) * 4 + b) * 256 + d8 * 8;
  const float* membase = memp + ((size_t)(srow * 4 + b)) * 256 + d8 * 8;

  float ta[2][4], la[2][4];
  #pragma unroll
  for (int j = 0; j < 2; ++j)
    #pragma unroll
    for (int u = 0; u < 4; ++u){ ta[j][u] = 0.f; la[j][u] = 0.f; }

  uint4 xw, yw;
  auto packxy = [&](const float4& r0, const float4& r1, const float4& m0, const float4& m1){
    float4 t20 = *(const float4*)&t2s[d8 * 8];
    float4 t21 = *(const float4*)&t2s[d8 * 8 + 4];
    xw.x = pk2(t20.x - m0.x + r0.x, t20.y - m0.y + r0.y);
    xw.y = pk2(t20.z - m0.z + r0.z, t20.w - m0.w + r0.w);
    xw.z = pk2(t21.x - m1.x + r1.x, t21.y - m1.y + r1.y);
    xw.w = pk2(t21.z - m1.z + r1.z, t21.w - m1.w + r1.w);
    yw.x = pk2(r0.x + m0.x, r0.y + m0.y);
    yw.y = pk2(r0.z + m0.z, r0.w + m0.w);
    yw.z = pk2(r1.x + m1.x, r1.y + m1.y);
    yw.w = pk2(r1.z + m1.z, r1.w + m1.w);
  };

  auto phase2 = [&](int pb){
    const char* hbp = (const char*)hb + pb * 8192;
    const char* ybp = (const char*)yb + pb * 8192;
    f32x4 accs[2] = {{0,0,0,0},{0,0,0,0}};
    f32x4 accv[2] = {{0,0,0,0},{0,0,0,0}};
    #pragma unroll
    for (int kc = 0; kc < 8; ++kc){
      int inb = l15 * 512 + ((kc * 64 + lg * 16) ^ (l15 << 4));
      short8 bh = *(const short8*)(hbp + inb);
      short8 by = *(const short8*)(ybp + inb);
      #pragma unroll
      for (int j = 0; j < 2; ++j){
        accs[j] = mfma16(w2r[j][kc], bh, accs[j]);
        accv[j] = mfma16(wvr[j][kc], by, accv[j]);
      }
    }
    #pragma unroll
    for (int j = 0; j < 2; ++j)
      #pragma unroll
      for (int u = 0; u < 4; ++u){
        float e = __expf(accs[j][u] * 0.0625f);
        ta[j][u] += e * accv[j][u];
        la[j][u] += e;
      }
  };

  // ---- prologue: tile 0 staged, loads for tile 1 in flight
  float4 r0 = *(const float4*)relbase;
  float4 r1 = *(const float4*)(relbase + 4);
  float4 m0 = *(const float4*)membase;
  float4 m1 = *(const float4*)(membase + 4);
  __syncthreads();                 // t2s/b1s visible
  packxy(r0, r1, m0, m1);
  *(uint4*)((char*)xb + toff) = xw;
  *(uint4*)((char*)yb + toff) = yw;
  r0 = *(const float4*)(relbase + 16384);
  r1 = *(const float4*)(relbase + 16384 + 4);
  m0 = *(const float4*)(membase + 16384);
  m1 = *(const float4*)(membase + 16384 + 4);

  for (int t = 0; t < 32; ++t){
    __syncthreads();               // barrier A: x/y(t), h(t-1) visible
    const char* xbp = (const char*)xb + (t & 1) * 8192;
    // ---- phase1: h(t) = relu(x@W1 + b1)
    f32x4 acch[2] = {{0,0,0,0},{0,0,0,0}};
    #pragma unroll
    for (int kc = 0; kc < 8; ++kc){
      short8 bx = *(const short8*)(xbp + l15 * 512 + ((kc * 64 + lg * 16) ^ (l15 << 4)));
      #pragma unroll
      for (int j = 0; j < 2; ++j)
        acch[j] = mfma16(w1r[j][kc], bx, acch[j]);
    }
    {
      char* hbp = (char*)hb + (t & 1) * 8192;
      #pragma unroll
      for (int j = 0; j < 2; ++j){
        float4 bb = *(const float4*)&b1s[w * 32 + j * 16 + lg * 4];
        uint2 hp;
        hp.x = pk2(fmaxf(acch[j][0] + bb.x, 0.f), fmaxf(acch[j][1] + bb.y, 0.f));
        hp.y = pk2(fmaxf(acch[j][2] + bb.z, 0.f), fmaxf(acch[j][3] + bb.w, 0.f));
        int inrow = (w * 64 + j * 32 + lg * 8) ^ (l15 << 4);
        *(uint2*)(hbp + l15 * 512 + inrow) = hp;
      }
    }
    // ---- pack tile t+1 (loads issued one iteration ago)
    if (t < 31) packxy(r0, r1, m0, m1);
    // ---- phase2: tile t-1
    if (t > 0) phase2((t - 1) & 1);
    if (t < 31){
      __syncthreads();             // barrier B: old-buffer reads done
      char* xbn = (char*)xb + ((t + 1) & 1) * 8192;
      char* ybn = (char*)yb + ((t + 1) & 1) * 8192;
      *(uint4*)(xbn + toff) = xw;
      *(uint4*)(ybn + toff) = yw;
      if (t < 30){
        size_t o = (size_t)(t + 2) * 16384;
        r0 = *(const float4*)(relbase + o);
        r1 = *(const float4*)(relbase + o + 4);
        m0 = *(const float4*)(membase + o);
        m1 = *(const float4*)(membase + o + 4);
      }
    }
  }
  __syncthreads();
  phase2(1);                       // tile 31

  // ---- reduce over the 16 c-lanes, add vb, write out
  #pragma unroll
  for (int j = 0; j < 2; ++j)
    #pragma unroll
    for (int u = 0; u < 4; ++u){
      #pragma unroll
      for (int m = 1; m <= 8; m <<= 1){
        ta[j][u] += __shfl_xor(ta[j][u], m, 64);
        la[j][u] += __shfl_xor(la[j][u], m, 64);
      }
    }
  if (l15 == 0){
    #pragma unroll
    for (int j = 0; j < 2; ++j){
      float4 vb4 = *(const float4*)(vbp + w * 32 + j * 16 + lg * 4);
      uint2 o;
      o.x = pk2(ta[j][0] / la[j][0] + vb4.x, ta[j][1] / la[j][1] + vb4.y);
      o.y = pk2(ta[j][2] / la[j][2] + vb4.z, ta[j][3] / la[j][3] + vb4.w);
      *(uint2*)(trel + (size_t)qb * 256 + w * 32 + j * 16 + lg * 4) = o;
    }
  }
}

// ---------------------------------------------------------------- launch
extern "C" void kernel_launch(void* const* d_in, const int* in_sizes, int n_in,
                              void* d_out, int out_size, void* d_ws, size_t ws_size,
                              hipStream_t stream)
{
  const float* tgt  = (const float*)d_in[0];
  const float* mem  = (const float*)d_in[1];
  const float* qpos = (const float*)d_in[2];
  const float* rel  = (const float*)d_in[3];
  const float* ln1g = (const float*)d_in[4];
  const float* ln1b = (const float*)d_in[5];
  const float* ln2g = (const float*)d_in[6];
  const float* ln2b = (const float*)d_in[7];
  const float* ln3g = (const float*)d_in[8];
  const float* ln3b = (const float*)d_in[9];
  const float* inw  = (const float*)d_in[10];
  const float* inb  = (const float*)d_in[11];
  const float* aow  = (const float*)d_in[12];
  const float* aob  = (const float*)d_in[13];
  const float* m1w  = (const float*)d_in[14];
  const float* m1b  = (const float*)d_in[15];
  const float* m2w  = (const float*)d_in[16];
  const float* m2b  = (const float*)d_in[17];
  const float* vw   = (const float*)d_in[18];
  const float* vb   = (const float*)d_in[19];
  const float* ow   = (const float*)d_in[20];
  const float* ob   = (const float*)d_in[21];
  const float* f1w  = (const float*)d_in[22];
  const float* f1b  = (const float*)d_in[23];
  const float* f2w  = (const float*)d_in[24];
  const float* f2b  = (const float*)d_in[25];

  char* ws = (char*)d_ws;
  size_t off = 0;
  auto alloc = [&](size_t bytes) -> char* {
    char* p = ws + off; off += (bytes + 255) & ~size_t(255); return p;
  };
  unsigned short* w1pk    = (unsigned short*)alloc(256 * 256 * 2);
  unsigned short* w2pk    = (unsigned short*)alloc(256 * 256 * 2);
  unsigned short* wvpk    = (unsigned short*)alloc(256 * 256 * 2);
  unsigned short* inw_bf  = (unsigned short*)alloc(768 * 256 * 2);
  unsigned short* aow_bf  = (unsigned short*)alloc(256 * 256 * 2);
  unsigned short* ow_bf   = (unsigned short*)alloc(256 * 256 * 2);
  unsigned short* f1w_bf  = (unsigned short*)alloc(1024 * 256 * 2);
  unsigned short* f2w_bf  = (unsigned short*)alloc(256 * 1024 * 2);
  unsigned short* t21_bf  = (unsigned short*)alloc(512 * 256 * 2);
  unsigned short* qk_bf   = (unsigned short*)alloc(512 * 256 * 2);
  float*          qkp     = (float*)alloc(512 * 512 * 4);
  float*          vp      = (float*)alloc(512 * 256 * 4);
  unsigned short* ao_bf   = (unsigned short*)alloc(512 * 256 * 2);
  float*          tgta    = (float*)alloc(512 * 256 * 4);
  float*          t22_f   = (float*)alloc(512 * 256 * 4);
  unsigned short* trel_bf = (unsigned short*)alloc(512 * 256 * 2);
  float*          tgtr    = (float*)alloc(512 * 256 * 4);
  unsigned short* t23_bf  = (unsigned short*)alloc(512 * 256 * 2);
  unsigned short* ffh_bf  = (unsigned short*)alloc(512 * 1024 * 2);

  conv_all_kernel<<<2048, 256, 0, stream>>>(inw, inw_bf, aow, aow_bf, ow, ow_bf,
      f1w, f1w_bf, f2w, f2w_bf, m1w, w1pk, m2w, w2pk, vw, wvpk);

  // ln1 -> tgt2_1 (bf16), qk = tgt2_1 + query_pos (bf16)
  ln_kernel<<<512, 256, 0, stream>>>(tgt, ln1g, ln1b, qpos, nullptr, t21_bf, qk_bf);

  // q|k projection (N=512) and v projection (N=256)
  gemm_kernel<<<dim3(8, 8), 256, 0, stream>>>(qk_bf, inw_bf, inb, nullptr,
      qkp, nullptr, 512, 512, 256, 1.f, 0);
  gemm_kernel<<<dim3(8, 4), 256, 0, stream>>>(t21_bf, inw_bf + 512 * 256, inb + 512, nullptr,
      vp, nullptr, 512, 256, 256, 1.f, 0);

  attn_kernel<<<32, 256, 0, stream>>>(qkp, vp, ao_bf);

  // out-proj + residual tgt -> tgta
  gemm_kernel<<<dim3(8, 4), 256, 0, stream>>>(ao_bf, aow_bf, aob, tgt,
      tgta, nullptr, 512, 256, 256, 1.f, 0);

  // ln2 -> t22 (f32)
  ln_kernel<<<512, 256, 0, stream>>>(tgta, ln2g, ln2b, nullptr, t22_f, nullptr, nullptr);

  // fused relation branch
  relfused_kernel<<<512, 512, 0, stream>>>(rel, mem, t22_f, w1pk, w2pk, wvpk,
      m1b, vb, trel_bf);

  // t = relu(t@o_w + o_b) + t22
  gemm_kernel<<<dim3(8, 4), 256, 0, stream>>>(trel_bf, ow_bf, ob, t22_f,
      tgtr, nullptr, 512, 256, 256, 1.f, 1);

  // ln3 -> bf16
  ln_kernel<<<512, 256, 0, stream>>>(tgtr, ln3g, ln3b, nullptr, nullptr, t23_bf, nullptr);

  // ffn
  gemm_kernel<<<dim3(8, 16), 256, 0, stream>>>(t23_bf, f1w_bf, f1b, nullptr,
      nullptr, ffh_bf, 512, 1024, 256, 1.f, 1);
  gemm_kernel<<<dim3(8, 4), 256, 0, stream>>>(ffh_bf, f2w_bf, f2b, tgtr,
      (float*)d_out, nullptr, 512, 256, 1024, 1.f, 0);
}